// Round 1
// baseline (538.186 us; speedup 1.0000x reference)
//
#include <hip/hip_runtime.h>

#ifndef INV_CELL_H
#define INV_CELL_H 20.0f
#endif

// Cubic B-spline basis + derivative for stencil offset idx in {0,1,2,3},
// where the spline argument is x = f + 1 - idx, f = frac(rel) in [0,1).
// Branches (from the reference's jnp.select) collapse per-offset:
//   idx=0: x in [1,2)   -> b = (2-x)^3/6          = g^3/6,            db = -h*g^2/2
//   idx=1: x in [0,1)   -> b = 2/3 - x^2 + x^3/2  (x=f),              db = -h*f*(2-1.5f)
//   idx=2: x in [-1,0)  -> b = 2/3 - x^2(1+x/2)   = 2/3 - g^2 + g^3/2, db = +h*g*(2-1.5g)
//   idx=3: x in [-2,-1) -> b = (2+x)^3/6          = f^3/6,            db = +h*f^2/2
// with g = 1 - f.  All selects are on lane-derived constants -> cndmask, no branches.
__device__ __forceinline__ void spline_eval(float f, float g, int idx,
                                            float& b, float& db) {
    float u  = (idx & 1) ? f : g;          // idx 0,2 use g; idx 1,3 use f
    float u2 = u * u;
    float u3 = u2 * u;
    bool outer = (idx == 0) || (idx == 3); // outer cells: cubic tail
    float b_out = u3 * (1.0f / 6.0f);
    float b_in  = fmaf(0.5f, u3, fmaf(-1.0f, u2, 2.0f / 3.0f)); // 2/3 - u^2 + u^3/2
    b = outer ? b_out : b_in;
    float m_out = 0.5f * u2;               // |db|/h outer
    float m_in  = u * fmaf(-1.5f, u, 2.0f);// u*(2-1.5u) inner
    float mag = outer ? m_out : m_in;
    float sgn = (idx >= 2) ? INV_CELL_H : -INV_CELL_H;
    db = mag * sgn;
}

struct F3 { float x, y, z; };

// One wave (64 lanes) per particle. lane = m = i*16 + j*4 + k matches the
// reference's meshgrid(ij) flattening. Each lane computes only its own
// (i,j,k) basis values -- no tables, no dynamic indexing.
__global__ void __launch_bounds__(256)
cubic_shapefn_kernel(const float* __restrict__ pos,
                     float* __restrict__ shapef,   // [N][64]
                     float* __restrict__ grad,     // [N][64][3]
                     int N) {
    int wave = blockIdx.x * 4 + (threadIdx.x >> 6);
    if (wave >= N) return;
    int lane = threadIdx.x & 63;

    // All 64 lanes read the same 3 floats; L1 broadcasts (12 B / wave).
    float px = pos[(size_t)wave * 3 + 0];
    float py = pos[(size_t)wave * 3 + 1];
    float pz = pos[(size_t)wave * 3 + 2];

    float rx = px * INV_CELL_H, ry = py * INV_CELL_H, rz = pz * INV_CELL_H;
    float fx = rx - floorf(rx), fy = ry - floorf(ry), fz = rz - floorf(rz);
    float gx = 1.0f - fx,       gy = 1.0f - fy,       gz = 1.0f - fz;

    int i = (lane >> 4) & 3;
    int j = (lane >> 2) & 3;
    int k = lane & 3;

    float bx, dbx, by, dby, bz, dbz;
    spline_eval(fx, gx, i, bx, dbx);
    spline_eval(fy, gy, j, by, dby);
    spline_eval(fz, gz, k, bz, dbz);

    float pyz = by * bz;
    float s   = bx * pyz;                 // shapef
    float gxv = dbx * pyz;                // d/dx
    float gyv = dby * (bx * bz);          // d/dy
    float gzv = dbz * (bx * by);          // d/dz

    // Coalesced: 64 consecutive floats per wave.
    shapef[(size_t)wave * 64 + lane] = s;

    // 12 B per lane; the wave covers the particle's full 768 B grad block
    // contiguously, so every 64 B line is fully written (no partial lines).
    F3 v{gxv, gyv, gzv};
    *(F3*)(grad + (size_t)wave * 192 + (size_t)lane * 3) = v;
}

extern "C" void kernel_launch(void* const* d_in, const int* in_sizes, int n_in,
                              void* d_out, int out_size, void* d_ws, size_t ws_size,
                              hipStream_t stream) {
    const float* pos = (const float*)d_in[0];
    int N = in_sizes[0] / 3;                       // 500,000
    float* shapef = (float*)d_out;                 // [N*64]
    float* grad   = shapef + (size_t)N * 64;       // [N*64*3]
    int blocks = (N + 3) / 4;                      // 4 waves/block, 1 particle/wave
    cubic_shapefn_kernel<<<blocks, 256, 0, stream>>>(pos, shapef, grad, N);
}